// Round 8
// baseline (362.557 us; speedup 1.0000x reference)
//
#include <hip/hip_runtime.h>

typedef __attribute__((ext_vector_type(4))) float  f32x4;
typedef __attribute__((ext_vector_type(8))) __bf16 bf16x8;
typedef __attribute__((ext_vector_type(4))) __bf16 bf16x4;

static __device__ __forceinline__ f32x4 mfma16(bf16x8 a, bf16x8 b, f32x4 c) {
  return __builtin_amdgcn_mfma_f32_16x16x32_bf16(a, b, c, 0, 0, 0);
}

typedef __attribute__((address_space(1))) const unsigned int* gas1_t;
typedef __attribute__((address_space(3))) unsigned int* las3_t;
static __device__ __forceinline__ void glds16(const void* g, void* l) {
  __builtin_amdgcn_global_load_lds((gas1_t)g, (las3_t)l, 16, 0, 0);
}

// Problem dims: B=16 L=2048 DM=512 S=1000(pad 1024) DL=1024 H=8 E=64 HE=512 DOUT=64
#define QSCALE 0.18033688011112042f   // (1/sqrt(64)) * log2(e)

// ---------------- prep 1: LDS-tiled weight transpose + bf16 convert ----------------
__global__ __launch_bounds__(256) void prep_wT(
    const float* __restrict__ Wq, const float* __restrict__ Wk,
    const float* __restrict__ Wv, const float* __restrict__ Wo,
    __bf16* __restrict__ wqT, __bf16* __restrict__ wkT,
    __bf16* __restrict__ wvT, __bf16* __restrict__ woT) {
  __shared__ float tile[32][33];
  const int t = blockIdx.x;
  const float* in; __bf16* out; int K, N, tk, tn;
  if (t < 256)       { in = Wq; out = wqT; K = 512;  N = 512; tk = t & 15;          tn = t >> 4; }
  else if (t < 768)  { in = Wk; out = wkT; K = 1024; N = 512; tk = (t-256) & 31;    tn = (t-256) >> 5; }
  else if (t < 1280) { in = Wv; out = wvT; K = 1024; N = 512; tk = (t-768) & 31;    tn = (t-768) >> 5; }
  else               { in = Wo; out = woT; K = 512;  N = 64;  tk = (t-1280) & 15;   tn = (t-1280) >> 4; }
  const int k0 = tk * 32, n0 = tn * 32;
  const int c = threadIdx.x & 31, r = threadIdx.x >> 5;   // r = 0..7
#pragma unroll
  for (int i = 0; i < 4; ++i)
    tile[r + i * 8][c] = in[(size_t)(k0 + r + i * 8) * N + n0 + c];
  __syncthreads();
#pragma unroll
  for (int i = 0; i < 4; ++i)
    out[(size_t)(n0 + r + i * 8) * K + k0 + c] = (__bf16)tile[c][r + i * 8];
}

// ---------------- prep 2: activation bf16 convert (src/val padded to 1024 rows) ----
__global__ __launch_bounds__(256) void prep_cvt(
    const float* __restrict__ tgt, const float* __restrict__ src,
    const float* __restrict__ val,
    __bf16* __restrict__ tgtb, __bf16* __restrict__ srcb, __bf16* __restrict__ valb) {
  const int j = blockIdx.x * 256 + threadIdx.x;
  const int C0 = 32768 * 512 / 4;
  const int CV = 1024 * 1024 / 4;
  if (j < C0) {
    f32x4 v = *(const f32x4*)&tgt[(size_t)j * 4];
    bf16x4 o; o[0]=(__bf16)v[0]; o[1]=(__bf16)v[1]; o[2]=(__bf16)v[2]; o[3]=(__bf16)v[3];
    *(bf16x4*)&tgtb[(size_t)j * 4] = o;
  } else if (j < C0 + 2 * CV) {
    const int which = (j - C0) / CV;            // 0 = src, 1 = val
    const int u = (j - C0) - which * CV;
    const float* in = which ? val : src;
    __bf16* outp = which ? valb : srcb;
    bf16x4 o;
    if (u * 4 < 1000 * 1024) {
      f32x4 v = *(const f32x4*)&in[(size_t)u * 4];
      o[0]=(__bf16)v[0]; o[1]=(__bf16)v[1]; o[2]=(__bf16)v[2]; o[3]=(__bf16)v[3];
    } else {
      o[0]=(__bf16)0.0f; o[1]=(__bf16)0.0f; o[2]=(__bf16)0.0f; o[3]=(__bf16)0.0f;
    }
    *(bf16x4*)&outp[(size_t)u * 4] = o;
  }
}

// ---------------- generic bf16 GEMM: C[M][N] = A[M][K] @ BT[N][K]^T ----------------
// 128x128 tile, 4 waves, BK=32, DOUBLE-BUFFERED: stage k+1 while computing k
// -> one barrier per K-step. glds16 with pre-swizzled global source (rule 21);
// fragment reads use the matching slot swizzle (2-way, free).
template <int MODE>
__global__ __launch_bounds__(256, 2) void gemm_bt(
    const __bf16* __restrict__ A, const __bf16* __restrict__ BT,
    const float* __restrict__ bias, float scale,
    __bf16* __restrict__ C, int M, int N, int K) {
  const int n0 = blockIdx.x * 128, m0 = blockIdx.y * 128;
  __shared__ __bf16 sA[2][128 * 32], sB[2][128 * 32];
  const int t = threadIdx.x;
  const int w = t >> 6, lane = t & 63;
  const int wr = w >> 1, wc = w & 1;
  const int lr = lane & 15, lg = lane >> 4;

  const int grow = w * 32 + (lane >> 2);
  const int lslot = (lane & 3) ^ ((lane >> 2) & 3) ^ (lane >> 4);
  const int woff = w * 2048;

  const int rslot = (lg ^ (lr & 3) ^ ((lr >> 2) & 3)) << 4;
  const int aOff = wr * 4096 + lr * 64 + rslot;   // + i*1024
  const int bOff = wc * 4096 + lr * 64 + rslot;

  f32x4 acc[4][4];
#pragma unroll
  for (int i = 0; i < 4; ++i)
#pragma unroll
    for (int j = 0; j < 4; ++j) acc[i][j] = f32x4{0.f, 0.f, 0.f, 0.f};

  const size_t gaBase0 = (size_t)(m0 + grow) * K + lslot * 8;
  const size_t gaBase1 = (size_t)(m0 + grow + 16) * K + lslot * 8;
  const size_t gbBase0 = (size_t)(n0 + grow) * K + lslot * 8;
  const size_t gbBase1 = (size_t)(n0 + grow + 16) * K + lslot * 8;

  // prologue: stage k-step 0 into buf 0
  glds16(&A[gaBase0], (char*)sA[0] + woff);
  glds16(&A[gaBase1], (char*)sA[0] + woff + 1024);
  glds16(&BT[gbBase0], (char*)sB[0] + woff);
  glds16(&BT[gbBase1], (char*)sB[0] + woff + 1024);
  __syncthreads();

  const int NK = K >> 5;
  for (int it = 0; it < NK; ++it) {
    const int cur = it & 1;
    if (it + 1 < NK) {                       // prefetch next k-step
      const int kc = (it + 1) << 5;
      glds16(&A[gaBase0 + kc], (char*)sA[cur ^ 1] + woff);
      glds16(&A[gaBase1 + kc], (char*)sA[cur ^ 1] + woff + 1024);
      glds16(&BT[gbBase0 + kc], (char*)sB[cur ^ 1] + woff);
      glds16(&BT[gbBase1 + kc], (char*)sB[cur ^ 1] + woff + 1024);
    }
    bf16x8 af[4], bfr[4];
#pragma unroll
    for (int i = 0; i < 4; ++i) {
      af[i]  = *(const bf16x8*)((const char*)sA[cur] + aOff + i * 1024);
      bfr[i] = *(const bf16x8*)((const char*)sB[cur] + bOff + i * 1024);
    }
    __builtin_amdgcn_s_setprio(1);
#pragma unroll
    for (int i = 0; i < 4; ++i)
#pragma unroll
      for (int j = 0; j < 4; ++j) acc[i][j] = mfma16(af[i], bfr[j], acc[i][j]);
    __builtin_amdgcn_s_setprio(0);
    __syncthreads();   // drains prefetch; protects buf swap both directions
  }

#pragma unroll
  for (int i = 0; i < 4; ++i) {
    const int rowb = m0 + wr * 64 + i * 16 + lg * 4;
#pragma unroll
    for (int j = 0; j < 4; ++j) {
      const int col = n0 + wc * 64 + j * 16 + lr;
      const float bb = bias ? bias[col] : 0.0f;
      if (MODE == 0) {
#pragma unroll
        for (int r = 0; r < 4; ++r)
          C[(size_t)(rowb + r) * N + col] = (__bf16)((acc[i][j][r] + bb) * scale);
      } else {
        bf16x4 v;
#pragma unroll
        for (int r = 0; r < 4; ++r) v[r] = (__bf16)((acc[i][j][r] + bb) * scale);
        *(bf16x4*)&C[(size_t)col * M + rowb] = v;
      }
    }
  }
}

// ---------------- flash attention v7 ----------------
// v6 + fixed epilogue: O^T fragments bounce through the per-wave sP LDS tile and
// are stored row-major with lanes contiguous (4 lanes x 16B = full 64B lines).
// v6's direct O^T store had 1024B lane stride -> zero write combining ->
// 211 MB HBM writes + RMW fetches (the round-6 regression).
__global__ __launch_bounds__(256, 4) void attn_kernel(
    const __bf16* __restrict__ qg, const __bf16* __restrict__ kg,
    const __bf16* __restrict__ vtg, __bf16* __restrict__ og) {
  const int bid = blockIdx.x;
  const int lt = bid & 15, h = (bid >> 4) & 7, b = bid >> 7;
  const int w = threadIdx.x >> 6, lane = threadIdx.x & 63;
  const int lr = lane & 15, g = lane >> 4, lr7 = lane & 7;
  const int l0 = lt * 128 + w * 32;

  __shared__ __bf16 sK[2][4096];   // [buf][64 s][64 e], 16B slots swizzled ^row&7
  __shared__ __bf16 sV[2][4096];   // [buf][64 e][64 s]
  __shared__ __bf16 sP[4][1024];   // per-wave [16 q][64 s] P^T / O-epilogue tile
  char* const pbase = (char*)&sP[w][0];

  const int srowi = lane >> 3;
  const int sslot = (lane & 7) ^ srowi;
  const int krow = w * 16 + srowi;
  const size_t kgBase = (size_t)krow * 512 + h * 64 + sslot * 8;     // + s*512
  const size_t vgBase = (size_t)(h * 64 + krow) * 1024 + sslot * 8;  // + s

  bf16x8 qf[2][2];
#pragma unroll
  for (int qi = 0; qi < 2; ++qi)
#pragma unroll
    for (int hf = 0; hf < 2; ++hf)
      qf[qi][hf] = *(const bf16x8*)&qg[
          ((size_t)b * 2048 + l0 + qi * 16 + lr) * 512 + h * 64 + hf * 32 + g * 8];

  f32x4 o[2][4], lsacc[2];
#pragma unroll
  for (int qi = 0; qi < 2; ++qi) {
#pragma unroll
    for (int j = 0; j < 4; ++j) o[qi][j] = f32x4{0.f, 0.f, 0.f, 0.f};
    lsacc[qi] = f32x4{0.f, 0.f, 0.f, 0.f};
  }

  bf16x8 ones8;
#pragma unroll
  for (int i = 0; i < 8; ++i) ones8[i] = (__bf16)1.0f;

  const int eOff0 = lr * 128 + ((g ^ lr7) << 4);
  const int pswz = lr7 << 4;

  glds16(&kg[kgBase], (char*)&sK[0][0] + w * 2048);
  glds16(&kg[kgBase + (size_t)8 * 512], (char*)&sK[0][0] + w * 2048 + 1024);
  glds16(&vtg[vgBase], (char*)&sV[0][0] + w * 2048);
  glds16(&vtg[vgBase + (size_t)8 * 1024], (char*)&sV[0][0] + w * 2048 + 1024);
  __syncthreads();

  for (int sc = 0; sc < 16; ++sc) {
    const int p = sc & 1;
    if (sc < 15) {                      // depth-1 async prefetch of chunk sc+1
      const int sn = (sc + 1) * 64;
      char* nk = (char*)&sK[p ^ 1][0] + w * 2048;
      char* nv = (char*)&sV[p ^ 1][0] + w * 2048;
      glds16(&kg[kgBase + (size_t)sn * 512], nk);
      glds16(&kg[kgBase + (size_t)(sn + 8) * 512], nk + 1024);
      glds16(&vtg[vgBase + sn], nv);
      glds16(&vtg[vgBase + sn + 8 * 1024], nv + 1024);
    }
    const char* kbuf = (const char*)&sK[p][0];
    const char* vbuf = (const char*)&sV[p][0];

    // QK^T (swapped): d[qi][t] -> score(s = sc*64 + t*16 + 4g + r, q = l0+qi*16+lr)
    bf16x8 kf[4][2];
#pragma unroll
    for (int t = 0; t < 4; ++t) {
      kf[t][0] = *(const bf16x8*)(kbuf + t * 2048 + eOff0);
      kf[t][1] = *(const bf16x8*)(kbuf + t * 2048 + (eOff0 ^ 64));
    }
    f32x4 d[2][4];
    __builtin_amdgcn_s_setprio(1);
#pragma unroll
    for (int qi = 0; qi < 2; ++qi)
#pragma unroll
      for (int t = 0; t < 4; ++t) {
        f32x4 z = {0.f, 0.f, 0.f, 0.f};
        z = mfma16(kf[t][0], qf[qi][0], z);
        z = mfma16(kf[t][1], qf[qi][1], z);
        d[qi][t] = z;
      }
    __builtin_amdgcn_s_setprio(0);
    if (sc == 15) {                     // mask padded keys s in [1000,1024)
#pragma unroll
      for (int qi = 0; qi < 2; ++qi)
#pragma unroll
        for (int t = 0; t < 4; ++t)
#pragma unroll
          for (int r = 0; r < 4; ++r)
            if (960 + t * 16 + 4 * g + r >= 1000) d[qi][t][r] = -1.0e30f;
    }

    // V fragments for both kc (A-operand of swapped PV)
    bf16x8 vf[2][4];
#pragma unroll
    for (int kc = 0; kc < 2; ++kc)
#pragma unroll
      for (int j = 0; j < 4; ++j)
        vf[kc][j] = *(const bf16x8*)(vbuf + j * 2048 + (eOff0 ^ (kc * 64)));

    // per qi: exp2 -> P^T LDS tile -> read as B-fragment -> ones-rowsum + PV
#pragma unroll
    for (int qi = 0; qi < 2; ++qi) {
#pragma unroll
      for (int t = 0; t < 4; ++t) {
        bf16x4 pv;
        pv[0] = (__bf16)exp2f(d[qi][t][0]);
        pv[1] = (__bf16)exp2f(d[qi][t][1]);
        pv[2] = (__bf16)exp2f(d[qi][t][2]);
        pv[3] = (__bf16)exp2f(d[qi][t][3]);
        *(bf16x4*)(pbase + lr * 128 + ((t * 32 + g * 8) ^ pswz)) = pv;
      }
#pragma unroll
      for (int kc = 0; kc < 2; ++kc) {
        const bf16x8 pB = *(const bf16x8*)(
            pbase + lr * 128 + ((kc * 64 + g * 16) ^ pswz));
        __builtin_amdgcn_s_setprio(1);
        lsacc[qi] = mfma16(ones8, pB, lsacc[qi]);
#pragma unroll
        for (int j = 0; j < 4; ++j)
          o[qi][j] = mfma16(vf[kc][j], pB, o[qi][j]);
        __builtin_amdgcn_s_setprio(0);
      }
    }
    __syncthreads();   // drains prefetch + K/V buffer handoff
  }

  // epilogue: O^T frags -> per-wave LDS tile -> coalesced row-major stores.
  // Same-wave DS ordering; no barrier. Lanes (row=lane>>2, chunk=lane&3) give
  // 4x16B = 64B contiguous per row -> full-line writes, no RMW.
  const int rr = lane >> 2, cc = lane & 3;
  const int rsw = (rr & 7) << 4;
#pragma unroll
  for (int qi = 0; qi < 2; ++qi) {
    const float rinv = 1.0f / lsacc[qi][0];
#pragma unroll
    for (int j = 0; j < 4; ++j) {
      bf16x4 v;
#pragma unroll
      for (int r = 0; r < 4; ++r) v[r] = (__bf16)(o[qi][j][r] * rinv);
      *(bf16x4*)(pbase + lr * 128 + ((j * 32 + g * 8) ^ pswz)) = v;
    }
    const uint4 lo = *(const uint4*)(pbase + rr * 128 + ((cc * 16) ^ rsw));
    const uint4 hi = *(const uint4*)(pbase + rr * 128 + ((cc * 16 + 64) ^ rsw));
    char* orow = (char*)&og[((size_t)b * 2048 + l0 + qi * 16 + rr) * 512 + h * 64];
    *(uint4*)(orow + cc * 16) = lo;
    *(uint4*)(orow + cc * 16 + 64) = hi;
  }
}

// ---------------- output projection: out[32768][64] = attn @ woT^T + bo (fp32) ----
__global__ __launch_bounds__(256) void out_proj(
    const __bf16* __restrict__ ab, const __bf16* __restrict__ woT,
    const float* __restrict__ bo, float* __restrict__ out) {
  const int w = threadIdx.x >> 6, lane = threadIdx.x & 63;
  const int lr = lane & 15, g = lane >> 4;
  const int r0 = blockIdx.x * 64 + w * 16;
  f32x4 acc[4];
#pragma unroll
  for (int j = 0; j < 4; ++j) acc[j] = f32x4{0.f, 0.f, 0.f, 0.f};
  for (int kc = 0; kc < 512; kc += 32) {
    const bf16x8 af = *(const bf16x8*)&ab[(size_t)(r0 + lr) * 512 + kc + g * 8];
#pragma unroll
    for (int j = 0; j < 4; ++j) {
      const bf16x8 bf = *(const bf16x8*)&woT[(size_t)(j * 16 + lr) * 512 + kc + g * 8];
      acc[j] = mfma16(af, bf, acc[j]);
    }
  }
#pragma unroll
  for (int j = 0; j < 4; ++j) {
    const int col = j * 16 + lr;
    const float bb = bo[col];
#pragma unroll
    for (int r = 0; r < 4; ++r)
      out[(size_t)(r0 + 4 * g + r) * 64 + col] = acc[j][r] + bb;
  }
}

extern "C" void kernel_launch(void* const* d_in, const int* in_sizes, int n_in,
                              void* d_out, int out_size, void* d_ws, size_t ws_size,
                              hipStream_t stream) {
  const float* tgt = (const float*)d_in[0];
  const float* src = (const float*)d_in[1];
  const float* val = (const float*)d_in[2];
  const float* Wq  = (const float*)d_in[3];
  const float* bq  = (const float*)d_in[4];
  const float* Wk  = (const float*)d_in[5];
  const float* bk  = (const float*)d_in[6];
  const float* Wv  = (const float*)d_in[7];
  const float* bv  = (const float*)d_in[8];
  const float* Wo  = (const float*)d_in[9];
  const float* bo  = (const float*)d_in[10];
  float* out = (float*)d_out;
  char* ws = (char*)d_ws;

  __bf16* wqT  = (__bf16*)(ws + 0);          //  512x512
  __bf16* wkT  = (__bf16*)(ws + 524288);     //  512x1024
  __bf16* wvT  = (__bf16*)(ws + 1572864);    //  512x1024
  __bf16* woT  = (__bf16*)(ws + 2621440);    //  64x512
  __bf16* srcb = (__bf16*)(ws + 2686976);    //  1024x1024 (rows >=1000 zero)
  __bf16* valb = (__bf16*)(ws + 4784128);    //  1024x1024
  __bf16* kb   = (__bf16*)(ws + 6881280);    //  1024x512   K[s][h*64+e]
  __bf16* vtb  = (__bf16*)(ws + 7929856);    //  512x1024   VT[h*64+e][s]
  __bf16* tgtb = (__bf16*)(ws + 8978432);    //  32768x512  (dead after Q gemm)
  __bf16* attnb= (__bf16*)(ws + 8978432);    //  aliases tgtb (disjoint liveness)
  __bf16* qb   = (__bf16*)(ws + 42532864);   //  32768x512

  prep_wT<<<1312, 256, 0, stream>>>(Wq, Wk, Wv, Wo, wqT, wkT, wvT, woT);
  prep_cvt<<<18432, 256, 0, stream>>>(tgt, src, val, tgtb, srcb, valb);

  gemm_bt<0><<<dim3(4, 256), 256, 0, stream>>>(tgtb, wqT, bq, QSCALE, qb, 32768, 512, 512);
  gemm_bt<0><<<dim3(4, 8), 256, 0, stream>>>(srcb, wkT, bk, 1.0f, kb, 1024, 512, 1024);
  gemm_bt<1><<<dim3(4, 8), 256, 0, stream>>>(valb, wvT, bv, 1.0f, vtb, 1024, 512, 1024);

  attn_kernel<<<2048, 256, 0, stream>>>(qb, kb, vtb, attnb);

  out_proj<<<512, 256, 0, stream>>>(attnb, woT, bo, out);
}

// Round 9
// 315.737 us; speedup vs baseline: 1.1483x; 1.1483x over previous
//
#include <hip/hip_runtime.h>

typedef __attribute__((ext_vector_type(4))) float  f32x4;
typedef __attribute__((ext_vector_type(8))) __bf16 bf16x8;
typedef __attribute__((ext_vector_type(4))) __bf16 bf16x4;

static __device__ __forceinline__ f32x4 mfma16(bf16x8 a, bf16x8 b, f32x4 c) {
  return __builtin_amdgcn_mfma_f32_16x16x32_bf16(a, b, c, 0, 0, 0);
}

typedef __attribute__((address_space(1))) const unsigned int* gas1_t;
typedef __attribute__((address_space(3))) unsigned int* las3_t;
static __device__ __forceinline__ void glds16(const void* g, void* l) {
  __builtin_amdgcn_global_load_lds((gas1_t)g, (las3_t)l, 16, 0, 0);
}

// Problem dims: B=16 L=2048 DM=512 S=1000(pad 1024) DL=1024 H=8 E=64 HE=512 DOUT=64
#define QSCALE 0.18033688011112042f   // (1/sqrt(64)) * log2(e)

// ---------------- prep 1: LDS-tiled weight transpose + bf16 convert ----------------
__global__ __launch_bounds__(256) void prep_wT(
    const float* __restrict__ Wq, const float* __restrict__ Wk,
    const float* __restrict__ Wv, const float* __restrict__ Wo,
    __bf16* __restrict__ wqT, __bf16* __restrict__ wkT,
    __bf16* __restrict__ wvT, __bf16* __restrict__ woT) {
  __shared__ float tile[32][33];
  const int t = blockIdx.x;
  const float* in; __bf16* out; int K, N, tk, tn;
  if (t < 256)       { in = Wq; out = wqT; K = 512;  N = 512; tk = t & 15;          tn = t >> 4; }
  else if (t < 768)  { in = Wk; out = wkT; K = 1024; N = 512; tk = (t-256) & 31;    tn = (t-256) >> 5; }
  else if (t < 1280) { in = Wv; out = wvT; K = 1024; N = 512; tk = (t-768) & 31;    tn = (t-768) >> 5; }
  else               { in = Wo; out = woT; K = 512;  N = 64;  tk = (t-1280) & 15;   tn = (t-1280) >> 4; }
  const int k0 = tk * 32, n0 = tn * 32;
  const int c = threadIdx.x & 31, r = threadIdx.x >> 5;   // r = 0..7
#pragma unroll
  for (int i = 0; i < 4; ++i)
    tile[r + i * 8][c] = in[(size_t)(k0 + r + i * 8) * N + n0 + c];
  __syncthreads();
#pragma unroll
  for (int i = 0; i < 4; ++i)
    out[(size_t)(n0 + r + i * 8) * K + k0 + c] = (__bf16)tile[c][r + i * 8];
}

// ---------------- prep 2: activation bf16 convert (src/val padded to 1024 rows) ----
__global__ __launch_bounds__(256) void prep_cvt(
    const float* __restrict__ tgt, const float* __restrict__ src,
    const float* __restrict__ val,
    __bf16* __restrict__ tgtb, __bf16* __restrict__ srcb, __bf16* __restrict__ valb) {
  const int j = blockIdx.x * 256 + threadIdx.x;
  const int C0 = 32768 * 512 / 4;
  const int CV = 1024 * 1024 / 4;
  if (j < C0) {
    f32x4 v = *(const f32x4*)&tgt[(size_t)j * 4];
    bf16x4 o; o[0]=(__bf16)v[0]; o[1]=(__bf16)v[1]; o[2]=(__bf16)v[2]; o[3]=(__bf16)v[3];
    *(bf16x4*)&tgtb[(size_t)j * 4] = o;
  } else if (j < C0 + 2 * CV) {
    const int which = (j - C0) / CV;            // 0 = src, 1 = val
    const int u = (j - C0) - which * CV;
    const float* in = which ? val : src;
    __bf16* outp = which ? valb : srcb;
    bf16x4 o;
    if (u * 4 < 1000 * 1024) {
      f32x4 v = *(const f32x4*)&in[(size_t)u * 4];
      o[0]=(__bf16)v[0]; o[1]=(__bf16)v[1]; o[2]=(__bf16)v[2]; o[3]=(__bf16)v[3];
    } else {
      o[0]=(__bf16)0.0f; o[1]=(__bf16)0.0f; o[2]=(__bf16)0.0f; o[3]=(__bf16)0.0f;
    }
    *(bf16x4*)&outp[(size_t)u * 4] = o;
  }
}

// ---------------- generic bf16 GEMM: C[M][N] = A[M][K] @ BT[N][K]^T ----------------
// 128x128 tile, 4 waves, BK=32, double-buffered (unchanged from round 7/8).
template <int MODE>
__global__ __launch_bounds__(256, 2) void gemm_bt(
    const __bf16* __restrict__ A, const __bf16* __restrict__ BT,
    const float* __restrict__ bias, float scale,
    __bf16* __restrict__ C, int M, int N, int K) {
  const int n0 = blockIdx.x * 128, m0 = blockIdx.y * 128;
  __shared__ __bf16 sA[2][128 * 32], sB[2][128 * 32];
  const int t = threadIdx.x;
  const int w = t >> 6, lane = t & 63;
  const int wr = w >> 1, wc = w & 1;
  const int lr = lane & 15, lg = lane >> 4;

  const int grow = w * 32 + (lane >> 2);
  const int lslot = (lane & 3) ^ ((lane >> 2) & 3) ^ (lane >> 4);
  const int woff = w * 2048;

  const int rslot = (lg ^ (lr & 3) ^ ((lr >> 2) & 3)) << 4;
  const int aOff = wr * 4096 + lr * 64 + rslot;   // + i*1024
  const int bOff = wc * 4096 + lr * 64 + rslot;

  f32x4 acc[4][4];
#pragma unroll
  for (int i = 0; i < 4; ++i)
#pragma unroll
    for (int j = 0; j < 4; ++j) acc[i][j] = f32x4{0.f, 0.f, 0.f, 0.f};

  const size_t gaBase0 = (size_t)(m0 + grow) * K + lslot * 8;
  const size_t gaBase1 = (size_t)(m0 + grow + 16) * K + lslot * 8;
  const size_t gbBase0 = (size_t)(n0 + grow) * K + lslot * 8;
  const size_t gbBase1 = (size_t)(n0 + grow + 16) * K + lslot * 8;

  // prologue: stage k-step 0 into buf 0
  glds16(&A[gaBase0], (char*)sA[0] + woff);
  glds16(&A[gaBase1], (char*)sA[0] + woff + 1024);
  glds16(&BT[gbBase0], (char*)sB[0] + woff);
  glds16(&BT[gbBase1], (char*)sB[0] + woff + 1024);
  __syncthreads();

  const int NK = K >> 5;
  for (int it = 0; it < NK; ++it) {
    const int cur = it & 1;
    if (it + 1 < NK) {                       // prefetch next k-step
      const int kc = (it + 1) << 5;
      glds16(&A[gaBase0 + kc], (char*)sA[cur ^ 1] + woff);
      glds16(&A[gaBase1 + kc], (char*)sA[cur ^ 1] + woff + 1024);
      glds16(&BT[gbBase0 + kc], (char*)sB[cur ^ 1] + woff);
      glds16(&BT[gbBase1 + kc], (char*)sB[cur ^ 1] + woff + 1024);
    }
    bf16x8 af[4], bfr[4];
#pragma unroll
    for (int i = 0; i < 4; ++i) {
      af[i]  = *(const bf16x8*)((const char*)sA[cur] + aOff + i * 1024);
      bfr[i] = *(const bf16x8*)((const char*)sB[cur] + bOff + i * 1024);
    }
    __builtin_amdgcn_s_setprio(1);
#pragma unroll
    for (int i = 0; i < 4; ++i)
#pragma unroll
      for (int j = 0; j < 4; ++j) acc[i][j] = mfma16(af[i], bfr[j], acc[i][j]);
    __builtin_amdgcn_s_setprio(0);
    __syncthreads();   // drains prefetch; protects buf swap both directions
  }

#pragma unroll
  for (int i = 0; i < 4; ++i) {
    const int rowb = m0 + wr * 64 + i * 16 + lg * 4;
#pragma unroll
    for (int j = 0; j < 4; ++j) {
      const int col = n0 + wc * 64 + j * 16 + lr;
      const float bb = bias ? bias[col] : 0.0f;
      if (MODE == 0) {
#pragma unroll
        for (int r = 0; r < 4; ++r)
          C[(size_t)(rowb + r) * N + col] = (__bf16)((acc[i][j][r] + bb) * scale);
      } else {
        bf16x4 v;
#pragma unroll
        for (int r = 0; r < 4; ++r) v[r] = (__bf16)((acc[i][j][r] + bb) * scale);
        *(bf16x4*)&C[(size_t)col * M + rowb] = v;
      }
    }
  }
}

// ---------------- flash attention v8 ----------------
// v7 with register-pressure relief: launch_bounds (256,3) (no 64-VGPR spill cap),
// kf loaded t-outer (one pair live), vf loaded per-kc inside PV (transient).
// v6/v7's 228 MB WRITE_SIZE was scratch-spill traffic from the (256,4) cap.
__global__ __launch_bounds__(256, 3) void attn_kernel(
    const __bf16* __restrict__ qg, const __bf16* __restrict__ kg,
    const __bf16* __restrict__ vtg, __bf16* __restrict__ og) {
  const int bid = blockIdx.x;
  const int lt = bid & 15, h = (bid >> 4) & 7, b = bid >> 7;
  const int w = threadIdx.x >> 6, lane = threadIdx.x & 63;
  const int lr = lane & 15, g = lane >> 4, lr7 = lane & 7;
  const int l0 = lt * 128 + w * 32;

  __shared__ __bf16 sK[2][4096];   // [buf][64 s][64 e], 16B slots swizzled ^row&7
  __shared__ __bf16 sV[2][4096];   // [buf][64 e][64 s]
  __shared__ __bf16 sP[4][1024];   // per-wave [16 q][64 s] P^T / O-epilogue tile
  char* const pbase = (char*)&sP[w][0];

  const int srowi = lane >> 3;
  const int sslot = (lane & 7) ^ srowi;
  const int krow = w * 16 + srowi;
  const size_t kgBase = (size_t)krow * 512 + h * 64 + sslot * 8;     // + s*512
  const size_t vgBase = (size_t)(h * 64 + krow) * 1024 + sslot * 8;  // + s

  bf16x8 qf[2][2];
#pragma unroll
  for (int qi = 0; qi < 2; ++qi)
#pragma unroll
    for (int hf = 0; hf < 2; ++hf)
      qf[qi][hf] = *(const bf16x8*)&qg[
          ((size_t)b * 2048 + l0 + qi * 16 + lr) * 512 + h * 64 + hf * 32 + g * 8];

  f32x4 o[2][4], lsacc[2];
#pragma unroll
  for (int qi = 0; qi < 2; ++qi) {
#pragma unroll
    for (int j = 0; j < 4; ++j) o[qi][j] = f32x4{0.f, 0.f, 0.f, 0.f};
    lsacc[qi] = f32x4{0.f, 0.f, 0.f, 0.f};
  }

  bf16x8 ones8;
#pragma unroll
  for (int i = 0; i < 8; ++i) ones8[i] = (__bf16)1.0f;

  const int eOff0 = lr * 128 + ((g ^ lr7) << 4);
  const int pswz = lr7 << 4;

  glds16(&kg[kgBase], (char*)&sK[0][0] + w * 2048);
  glds16(&kg[kgBase + (size_t)8 * 512], (char*)&sK[0][0] + w * 2048 + 1024);
  glds16(&vtg[vgBase], (char*)&sV[0][0] + w * 2048);
  glds16(&vtg[vgBase + (size_t)8 * 1024], (char*)&sV[0][0] + w * 2048 + 1024);
  __syncthreads();

  for (int sc = 0; sc < 16; ++sc) {
    const int p = sc & 1;
    if (sc < 15) {                      // depth-1 async prefetch of chunk sc+1
      const int sn = (sc + 1) * 64;
      char* nk = (char*)&sK[p ^ 1][0] + w * 2048;
      char* nv = (char*)&sV[p ^ 1][0] + w * 2048;
      glds16(&kg[kgBase + (size_t)sn * 512], nk);
      glds16(&kg[kgBase + (size_t)(sn + 8) * 512], nk + 1024);
      glds16(&vtg[vgBase + sn], nv);
      glds16(&vtg[vgBase + sn + 8 * 1024], nv + 1024);
    }
    const char* kbuf = (const char*)&sK[p][0];
    const char* vbuf = (const char*)&sV[p][0];

    // QK^T (swapped), t-outer so only one kf pair is live at a time:
    // d[qi][t] -> score(s = sc*64 + t*16 + 4g + r, q = l0 + qi*16 + lr)
    f32x4 d[2][4];
#pragma unroll
    for (int t = 0; t < 4; ++t) {
      const bf16x8 kf0 = *(const bf16x8*)(kbuf + t * 2048 + eOff0);
      const bf16x8 kf1 = *(const bf16x8*)(kbuf + t * 2048 + (eOff0 ^ 64));
      __builtin_amdgcn_s_setprio(1);
#pragma unroll
      for (int qi = 0; qi < 2; ++qi) {
        f32x4 z = {0.f, 0.f, 0.f, 0.f};
        z = mfma16(kf0, qf[qi][0], z);
        z = mfma16(kf1, qf[qi][1], z);
        d[qi][t] = z;
      }
      __builtin_amdgcn_s_setprio(0);
    }
    if (sc == 15) {                     // mask padded keys s in [1000,1024)
#pragma unroll
      for (int qi = 0; qi < 2; ++qi)
#pragma unroll
        for (int t = 0; t < 4; ++t)
#pragma unroll
          for (int r = 0; r < 4; ++r)
            if (960 + t * 16 + 4 * g + r >= 1000) d[qi][t][r] = -1.0e30f;
    }

    // per qi: exp2 -> P^T LDS tile -> read back as B-fragment; vf per-kc
#pragma unroll
    for (int qi = 0; qi < 2; ++qi) {
#pragma unroll
      for (int t = 0; t < 4; ++t) {
        bf16x4 pv;
        pv[0] = (__bf16)exp2f(d[qi][t][0]);
        pv[1] = (__bf16)exp2f(d[qi][t][1]);
        pv[2] = (__bf16)exp2f(d[qi][t][2]);
        pv[3] = (__bf16)exp2f(d[qi][t][3]);
        *(bf16x4*)(pbase + lr * 128 + ((t * 32 + g * 8) ^ pswz)) = pv;
      }
#pragma unroll
      for (int kc = 0; kc < 2; ++kc) {
        bf16x8 vf0 = *(const bf16x8*)(vbuf + 0 * 2048 + (eOff0 ^ (kc * 64)));
        bf16x8 vf1 = *(const bf16x8*)(vbuf + 1 * 2048 + (eOff0 ^ (kc * 64)));
        bf16x8 vf2 = *(const bf16x8*)(vbuf + 2 * 2048 + (eOff0 ^ (kc * 64)));
        bf16x8 vf3 = *(const bf16x8*)(vbuf + 3 * 2048 + (eOff0 ^ (kc * 64)));
        const bf16x8 pB = *(const bf16x8*)(
            pbase + lr * 128 + ((kc * 64 + g * 16) ^ pswz));
        __builtin_amdgcn_s_setprio(1);
        lsacc[qi] = mfma16(ones8, pB, lsacc[qi]);
        o[qi][0] = mfma16(vf0, pB, o[qi][0]);
        o[qi][1] = mfma16(vf1, pB, o[qi][1]);
        o[qi][2] = mfma16(vf2, pB, o[qi][2]);
        o[qi][3] = mfma16(vf3, pB, o[qi][3]);
        __builtin_amdgcn_s_setprio(0);
      }
    }
    __syncthreads();   // drains prefetch + K/V buffer handoff
  }

  // epilogue: O^T frags -> per-wave LDS tile -> coalesced row-major stores.
  const int rr = lane >> 2, cc = lane & 3;
  const int rsw = (rr & 7) << 4;
#pragma unroll
  for (int qi = 0; qi < 2; ++qi) {
    const float rinv = 1.0f / lsacc[qi][0];
#pragma unroll
    for (int j = 0; j < 4; ++j) {
      bf16x4 v;
#pragma unroll
      for (int r = 0; r < 4; ++r) v[r] = (__bf16)(o[qi][j][r] * rinv);
      *(bf16x4*)(pbase + lr * 128 + ((j * 32 + g * 8) ^ pswz)) = v;
    }
    const uint4 lo = *(const uint4*)(pbase + rr * 128 + ((cc * 16) ^ rsw));
    const uint4 hi = *(const uint4*)(pbase + rr * 128 + ((cc * 16 + 64) ^ rsw));
    char* orow = (char*)&og[((size_t)b * 2048 + l0 + qi * 16 + rr) * 512 + h * 64];
    *(uint4*)(orow + cc * 16) = lo;
    *(uint4*)(orow + cc * 16 + 64) = hi;
  }
}

// ---------------- output projection: out[32768][64] = attn @ woT^T + bo (fp32) ----
__global__ __launch_bounds__(256) void out_proj(
    const __bf16* __restrict__ ab, const __bf16* __restrict__ woT,
    const float* __restrict__ bo, float* __restrict__ out) {
  const int w = threadIdx.x >> 6, lane = threadIdx.x & 63;
  const int lr = lane & 15, g = lane >> 4;
  const int r0 = blockIdx.x * 64 + w * 16;
  f32x4 acc[4];
#pragma unroll
  for (int j = 0; j < 4; ++j) acc[j] = f32x4{0.f, 0.f, 0.f, 0.f};
  for (int kc = 0; kc < 512; kc += 32) {
    const bf16x8 af = *(const bf16x8*)&ab[(size_t)(r0 + lr) * 512 + kc + g * 8];
#pragma unroll
    for (int j = 0; j < 4; ++j) {
      const bf16x8 bf = *(const bf16x8*)&woT[(size_t)(j * 16 + lr) * 512 + kc + g * 8];
      acc[j] = mfma16(af, bf, acc[j]);
    }
  }
#pragma unroll
  for (int j = 0; j < 4; ++j) {
    const int col = j * 16 + lr;
    const float bb = bo[col];
#pragma unroll
    for (int r = 0; r < 4; ++r)
      out[(size_t)(r0 + 4 * g + r) * 64 + col] = acc[j][r] + bb;
  }
}

extern "C" void kernel_launch(void* const* d_in, const int* in_sizes, int n_in,
                              void* d_out, int out_size, void* d_ws, size_t ws_size,
                              hipStream_t stream) {
  const float* tgt = (const float*)d_in[0];
  const float* src = (const float*)d_in[1];
  const float* val = (const float*)d_in[2];
  const float* Wq  = (const float*)d_in[3];
  const float* bq  = (const float*)d_in[4];
  const float* Wk  = (const float*)d_in[5];
  const float* bk  = (const float*)d_in[6];
  const float* Wv  = (const float*)d_in[7];
  const float* bv  = (const float*)d_in[8];
  const float* Wo  = (const float*)d_in[9];
  const float* bo  = (const float*)d_in[10];
  float* out = (float*)d_out;
  char* ws = (char*)d_ws;

  __bf16* wqT  = (__bf16*)(ws + 0);          //  512x512
  __bf16* wkT  = (__bf16*)(ws + 524288);     //  512x1024
  __bf16* wvT  = (__bf16*)(ws + 1572864);    //  512x1024
  __bf16* woT  = (__bf16*)(ws + 2621440);    //  64x512
  __bf16* srcb = (__bf16*)(ws + 2686976);    //  1024x1024 (rows >=1000 zero)
  __bf16* valb = (__bf16*)(ws + 4784128);    //  1024x1024
  __bf16* kb   = (__bf16*)(ws + 6881280);    //  1024x512   K[s][h*64+e]
  __bf16* vtb  = (__bf16*)(ws + 7929856);    //  512x1024   VT[h*64+e][s]
  __bf16* tgtb = (__bf16*)(ws + 8978432);    //  32768x512  (dead after Q gemm)
  __bf16* attnb= (__bf16*)(ws + 8978432);    //  aliases tgtb (disjoint liveness)
  __bf16* qb   = (__bf16*)(ws + 42532864);   //  32768x512

  prep_wT<<<1312, 256, 0, stream>>>(Wq, Wk, Wv, Wo, wqT, wkT, wvT, woT);
  prep_cvt<<<18432, 256, 0, stream>>>(tgt, src, val, tgtb, srcb, valb);

  gemm_bt<0><<<dim3(4, 256), 256, 0, stream>>>(tgtb, wqT, bq, QSCALE, qb, 32768, 512, 512);
  gemm_bt<0><<<dim3(4, 8), 256, 0, stream>>>(srcb, wkT, bk, 1.0f, kb, 1024, 512, 1024);
  gemm_bt<1><<<dim3(4, 8), 256, 0, stream>>>(valb, wvT, bv, 1.0f, vtb, 1024, 512, 1024);

  attn_kernel<<<2048, 256, 0, stream>>>(qb, kb, vtb, attnb);

  out_proj<<<512, 256, 0, stream>>>(attnb, woT, bo, out);
}